// Round 17
// baseline (732.539 us; speedup 1.0000x reference)
//
#include <hip/hip_runtime.h>

#define N_NODES 100000
#define N_EDGES 1600000
#define CAP 64

typedef unsigned short ushort_t;
typedef __attribute__((ext_vector_type(8))) short bf16x8;
typedef __attribute__((ext_vector_type(4))) float f32x4;
typedef __attribute__((ext_vector_type(4))) int int4e;
typedef __attribute__((ext_vector_type(8))) unsigned short ushort8e;

__device__ __forceinline__ unsigned short f2bf(float f) {
  unsigned int u = __float_as_uint(f);
  u = (u + 0x7FFFu + ((u >> 16) & 1u)) >> 16;
  return (unsigned short)u;
}

// ---- fused preprocessing, role-interleaved by (bid & 7): roles 0-1 deg atomics,
// roles 2-3 bucket scatter (raw ew), 4-7 pack X,H -> U bf16 + B^T/bias ----
__global__ __launch_bounds__(256) void k_misc(
    const int* __restrict__ ei, const float* __restrict__ ew,
    const float* __restrict__ X, const float* __restrict__ H,
    float* __restrict__ deg, int* __restrict__ cnt, int2* __restrict__ bE,
    ushort_t* __restrict__ U,
    const float* __restrict__ W, const float* __restrict__ b,
    const float* __restrict__ cW, const float* __restrict__ cb,
    ushort_t* __restrict__ Bt, float* __restrict__ bias) {
  int bid = blockIdx.x;
  int role = bid & 7, q = bid >> 3;          // q < 3391
  if (role < 2) {                            // deg atomics
    int e = (q * 2 + role) * 256 + threadIdx.x;
    if (e < N_EDGES) atomicAdd(&deg[ei[e]], ew[e]);
  } else if (role < 4) {                     // bucket by dst: (row, raw ew)
    int e = (q * 2 + (role - 2)) * 256 + threadIdx.x;
    if (e < N_EDGES) {
      int r = ei[e], c = ei[N_EDGES + e];
      float w = ew[e];
      int pos = atomicAdd(&cnt[c], 1);
      if (pos < CAP) bE[c * CAP + pos] = make_int2(r, __float_as_int(w));
    }
  } else {                                   // streaming: pack then bt
    int s = q * 4 + (role - 4);              // s < 13564
    if (s < 12500) {                         // pack X (cols 0-127), H (128-255)
      int i = s * 256 + threadIdx.x;         // i < 3.2M exactly
      int n = i >> 5, qq = i & 31;
      float4 x = *(const float4*)(X + (size_t)n * 128 + qq * 4);
      float4 h = *(const float4*)(H + (size_t)n * 128 + qq * 4);
      ushort4 a, bb;
      a.x = f2bf(x.x); a.y = f2bf(x.y); a.z = f2bf(x.z); a.w = f2bf(x.w);
      bb.x = f2bf(h.x); bb.y = f2bf(h.y); bb.z = f2bf(h.z); bb.w = f2bf(h.w);
      *(ushort4*)(U + (size_t)n * 512 + qq * 4) = a;
      *(ushort4*)(U + (size_t)n * 512 + 128 + qq * 4) = bb;
    } else if (s < 13524) {                  // B^T [512 j][512 k], j = d*4+g; bias
      int idx = (s - 12500) * 256 + threadIdx.x;
      int j = idx >> 9, k = idx & 511;
      int dd = j >> 2, g = j & 3;
      float v;
      if (k < 128) v = W[(g * 128 + k) * 128 + dd];
      else {
        int kk = k - 128;
        int blk = kk >> 7;
        v = cW[((g * 3 + blk) * 128 + (kk & 127)) * 128 + dd];
      }
      Bt[idx] = f2bf(v);
      if (k == 0) bias[j] = b[g * 128 + dd] + cb[g * 128 + dd];
    }
  }
}

// ---- post-pass: bE[slot].w = rsqrt(deg[row]) * raw_ew (deg now complete) ----
__global__ __launch_bounds__(256) void k_scale(
    const int* __restrict__ cnt, const float* __restrict__ deg,
    int2* __restrict__ bE) {
  int slot = blockIdx.x * 256 + threadIdx.x;     // grid covers N_NODES*CAP exactly
  int node = slot >> 6, i = slot & 63;
  int cn = cnt[node]; if (cn > CAP) cn = CAP;
  if (i < cn) {
    int2 p = bE[slot];
    float d = deg[p.x];
    float w = d > 0.f ? rsqrtf(d) * __int_as_float(p.y) : 0.f;
    bE[slot].y = __float_as_int(w);
  }
}

// FMA of one bf16-packed row (int4e = 8 bf16) into 8-col accumulator A
#define FMA8(A, Wt, R) { \
  A[0] = fmaf(Wt, __uint_as_float((unsigned)R.x << 16), A[0]); \
  A[1] = fmaf(Wt, __uint_as_float((unsigned)R.x & 0xffff0000u), A[1]); \
  A[2] = fmaf(Wt, __uint_as_float((unsigned)R.y << 16), A[2]); \
  A[3] = fmaf(Wt, __uint_as_float((unsigned)R.y & 0xffff0000u), A[3]); \
  A[4] = fmaf(Wt, __uint_as_float((unsigned)R.z << 16), A[4]); \
  A[5] = fmaf(Wt, __uint_as_float((unsigned)R.z & 0xffff0000u), A[5]); \
  A[6] = fmaf(Wt, __uint_as_float((unsigned)R.w << 16), A[6]); \
  A[7] = fmaf(Wt, __uint_as_float((unsigned)R.w & 0xffff0000u), A[7]); }

// ---- XCD col-sharded bf16 gather: slice = bid&7 owns 16 bf16 cols; 2 lanes/node
// (8 cols = 16B each); 128 nodes/block. Per-XCD source slice = 3.2MB -> L2-fit.
// PHASE 1: T1 = L_hat @ bf16(H)   (src U+128) -> U cols 256..383
// PHASE 2: T2 = 2*L_hat @ bf16(T1) - H (src U+256) -> U cols 384..511
template <int PHASE>
__global__ __launch_bounds__(256) void k_gather(
    const int* __restrict__ cnt, const int2* __restrict__ bE,
    const float* __restrict__ deg, const float* __restrict__ H,
    ushort_t* __restrict__ U) {
  int slice = blockIdx.x & 7, ng = blockIdx.x >> 3;
  int g = threadIdx.x >> 1, lane = threadIdx.x & 1;
  int node = ng * 128 + g;
  if (node >= N_NODES) return;
  int cn = cnt[node]; if (cn > CAP) cn = CAP;
  const int2* be = bE + node * CAP;
  const ushort_t* sb = U + (PHASE == 1 ? 128 : 256) + slice * 16 + lane * 8;
  float dc = deg[node];
  float sc = dc > 0.f ? -rsqrtf(dc) : 0.f;   // -dinv[c], factored out of the sum

  float a0[8] = {}, a1[8] = {}, a2[8] = {}, a3[8] = {};
  float a4[8] = {}, a5[8] = {}, a6[8] = {}, a7[8] = {};
  int i = 0;
  for (; i + 8 <= cn; i += 8) {
    int4e p0 = __builtin_nontemporal_load((const int4e*)(be + i));
    int4e p1 = __builtin_nontemporal_load((const int4e*)(be + i + 2));
    int4e p2 = __builtin_nontemporal_load((const int4e*)(be + i + 4));
    int4e p3 = __builtin_nontemporal_load((const int4e*)(be + i + 6));
    int4e r0 = *(const int4e*)(sb + (size_t)p0.x * 512);
    int4e r1 = *(const int4e*)(sb + (size_t)p0.z * 512);
    int4e r2 = *(const int4e*)(sb + (size_t)p1.x * 512);
    int4e r3 = *(const int4e*)(sb + (size_t)p1.z * 512);
    int4e r4 = *(const int4e*)(sb + (size_t)p2.x * 512);
    int4e r5 = *(const int4e*)(sb + (size_t)p2.z * 512);
    int4e r6 = *(const int4e*)(sb + (size_t)p3.x * 512);
    int4e r7 = *(const int4e*)(sb + (size_t)p3.z * 512);
    FMA8(a0, __int_as_float(p0.y), r0); FMA8(a1, __int_as_float(p0.w), r1);
    FMA8(a2, __int_as_float(p1.y), r2); FMA8(a3, __int_as_float(p1.w), r3);
    FMA8(a4, __int_as_float(p2.y), r4); FMA8(a5, __int_as_float(p2.w), r5);
    FMA8(a6, __int_as_float(p3.y), r6); FMA8(a7, __int_as_float(p3.w), r7);
  }
  for (; i + 4 <= cn; i += 4) {
    int4e p0 = __builtin_nontemporal_load((const int4e*)(be + i));
    int4e p1 = __builtin_nontemporal_load((const int4e*)(be + i + 2));
    int4e r0 = *(const int4e*)(sb + (size_t)p0.x * 512);
    int4e r1 = *(const int4e*)(sb + (size_t)p0.z * 512);
    int4e r2 = *(const int4e*)(sb + (size_t)p1.x * 512);
    int4e r3 = *(const int4e*)(sb + (size_t)p1.z * 512);
    FMA8(a0, __int_as_float(p0.y), r0); FMA8(a1, __int_as_float(p0.w), r1);
    FMA8(a2, __int_as_float(p1.y), r2); FMA8(a3, __int_as_float(p1.w), r3);
  }
  for (; i < cn; ++i) {
    int2 p = be[i];
    int4e r0 = *(const int4e*)(sb + (size_t)p.x * 512);
    FMA8(a0, __int_as_float(p.y), r0);
  }
  float o[8];
#pragma unroll
  for (int j = 0; j < 8; ++j)
    o[j] = sc * (((a0[j] + a1[j]) + (a2[j] + a3[j])) +
                 ((a4[j] + a5[j]) + (a6[j] + a7[j])));

  if (PHASE == 1) {
    ushort8e u;
#pragma unroll
    for (int j = 0; j < 8; ++j) u[j] = f2bf(o[j]);
    __builtin_nontemporal_store(u,
        (ushort8e*)(U + (size_t)node * 512 + 256 + slice * 16 + lane * 8));
  } else {
    float4 hlo = *(const float4*)(H + (size_t)node * 128 + slice * 16 + lane * 8);
    float4 hhi = *(const float4*)(H + (size_t)node * 128 + slice * 16 + lane * 8 + 4);
    ushort8e u;
    u[0] = f2bf(2.f * o[0] - hlo.x); u[1] = f2bf(2.f * o[1] - hlo.y);
    u[2] = f2bf(2.f * o[2] - hlo.z); u[3] = f2bf(2.f * o[3] - hlo.w);
    u[4] = f2bf(2.f * o[4] - hhi.x); u[5] = f2bf(2.f * o[5] - hhi.y);
    u[6] = f2bf(2.f * o[6] - hhi.z); u[7] = f2bf(2.f * o[7] - hhi.w);
    __builtin_nontemporal_store(u,
        (ushort8e*)(U + (size_t)node * 512 + 384 + slice * 16 + lane * 8));
  }
}

// ---- fused GEMM: 2-phase counted-vmcnt pipeline, 512 threads (8 waves of
// 32x64) on the 128x128 tile -> 16 waves/CU at 64KB LDS ----
__global__ __launch_bounds__(512, 4) void k_gemm(
    const ushort_t* __restrict__ U, const ushort_t* __restrict__ Bt,
    const float* __restrict__ bias, const float* __restrict__ C,
    float* __restrict__ out) {
  __shared__ char ldsRaw[65536];     // 2 x (16K A + 16K B); epilogue reuses as f32 tile
  char* ldsA0 = ldsRaw;
  char* ldsB0 = ldsRaw + 16384;
  char* ldsA1 = ldsRaw + 32768;
  char* ldsB1 = ldsRaw + 49152;
  float* ldsF = (float*)ldsRaw;

  const int tid = threadIdx.x;
  const int lane = tid & 63;
  const int w = tid >> 6;            // 8 waves
  const int wr = w >> 1, wc = w & 1; // 4x2 wave grid: 32-row x 64-col sub-tiles
  // XCD-bijective swizzle: 3128 = 8*391; 4 n-tiles of an m-panel stay in one XCD
  const int b = blockIdx.x;
  const int g = (b & 7) * 391 + (b >> 3);
  const int m0 = (g >> 2) * 128;
  const int n0 = (g & 3) * 128;
  const int l15 = lane & 15;
  const int l4 = lane >> 4;

  // stage half h of tile kt: each thread 1 A + 1 B global_load_lds (16B)
  auto stage_half = [&](int kt, char* la_base, char* lb_base, int h) {
    const int k0 = kt * 64;
    int s = h * 512 + tid;
    int row = s >> 3;
    int cs = (s & 7) ^ (row & 7);          // inverse-swizzled global source chunk
    const ushort_t* ga = U + (size_t)(m0 + row) * 512 + k0 + cs * 8;
    const ushort_t* gb = Bt + (size_t)(n0 + row) * 512 + k0 + cs * 8;
    char* la = la_base + (h * 512 + (tid & 448)) * 16;    // wave-uniform base
    char* lb = lb_base + (h * 512 + (tid & 448)) * 16;
    __builtin_amdgcn_global_load_lds((const __attribute__((address_space(1))) void*)ga,
                                     (__attribute__((address_space(3))) void*)la, 16, 0, 0);
    __builtin_amdgcn_global_load_lds((const __attribute__((address_space(1))) void*)gb,
                                     (__attribute__((address_space(3))) void*)lb, 16, 0, 0);
  };

  // C prefetch (epilogue operand), nontemporal (single-touch, keep out of L2)
  const int fcol = tid & 31;
  const int rbase = tid >> 5;              // 0..15
  float cpre[8];
#pragma unroll
  for (int half = 0; half < 2; ++half)
#pragma unroll
    for (int k = 0; k < 4; ++k) {
      int n = m0 + half * 64 + rbase + k * 16;
      int dg = (n0 >> 2) + fcol;
      cpre[half * 4 + k] = (n < N_NODES)
          ? __builtin_nontemporal_load(C + (size_t)n * 128 + dg) : 0.f;
    }

  // loop-invariant swizzled LDS read offsets (sub-tile rows are multiples of 16)
  int offA[2][2], offB[2][4];
#pragma unroll
  for (int ks = 0; ks < 2; ++ks) {
    int slot = ((ks * 4 + l4) ^ (l15 & 7)) * 16;
#pragma unroll
    for (int i = 0; i < 2; ++i)
      offA[ks][i] = (wr * 32 + i * 16 + l15) * 128 + slot;
#pragma unroll
    for (int i = 0; i < 4; ++i)
      offB[ks][i] = (wc * 64 + i * 16 + l15) * 128 + slot;
  }

  f32x4 acc[2][4] = {};

  stage_half(0, ldsA0, ldsB0, 0);
  stage_half(0, ldsA0, ldsB0, 1);          // 4 loads/thread outstanding

  for (int kt = 0; kt < 8; ++kt) {
    char* curA = (kt & 1) ? ldsA1 : ldsA0;
    char* curB = (kt & 1) ? ldsB1 : ldsB0;
    char* nA = (kt & 1) ? ldsA0 : ldsA1;
    char* nB = (kt & 1) ? ldsB0 : ldsB1;
    if (kt < 7) {
      stage_half(kt + 1, nA, nB, 0);       // 2 loads -> 6 outstanding
      asm volatile("s_waitcnt vmcnt(2)" ::: "memory");  // stage(kt) landed; half0(kt+1) in flight
    } else {
      asm volatile("s_waitcnt vmcnt(0)" ::: "memory");
    }
    __builtin_amdgcn_s_barrier();          // A: cur fully staged for all threads
    __builtin_amdgcn_sched_barrier(0);

    // ---- sub-phase ks=0 ----
    {
      bf16x8 af[2], bfr[4];
#pragma unroll
      for (int mi = 0; mi < 2; ++mi) af[mi] = *(const bf16x8*)(curA + offA[0][mi]);
#pragma unroll
      for (int ni = 0; ni < 4; ++ni) bfr[ni] = *(const bf16x8*)(curB + offB[0][ni]);
      asm volatile("s_waitcnt lgkmcnt(0)" ::: "memory");
      __builtin_amdgcn_sched_barrier(0);
      __builtin_amdgcn_s_setprio(1);
#pragma unroll
      for (int mi = 0; mi < 2; ++mi)
#pragma unroll
        for (int ni = 0; ni < 4; ++ni)
          acc[mi][ni] = __builtin_amdgcn_mfma_f32_16x16x32_bf16(af[mi], bfr[ni], acc[mi][ni], 0, 0, 0);
      __builtin_amdgcn_s_setprio(0);
    }
    if (kt < 7) stage_half(kt + 1, nA, nB, 1);  // 2 loads
    // ---- sub-phase ks=1 ----
    {
      bf16x8 af[2], bfr[4];
#pragma unroll
      for (int mi = 0; mi < 2; ++mi) af[mi] = *(const bf16x8*)(curA + offA[1][mi]);
#pragma unroll
      for (int ni = 0; ni < 4; ++ni) bfr[ni] = *(const bf16x8*)(curB + offB[1][ni]);
      asm volatile("s_waitcnt lgkmcnt(0)" ::: "memory");
      __builtin_amdgcn_sched_barrier(0);
      __builtin_amdgcn_s_setprio(1);
#pragma unroll
      for (int mi = 0; mi < 2; ++mi)
#pragma unroll
        for (int ni = 0; ni < 4; ++ni)
          acc[mi][ni] = __builtin_amdgcn_mfma_f32_16x16x32_bf16(af[mi], bfr[ni], acc[mi][ni], 0, 0, 0);
      __builtin_amdgcn_s_setprio(0);
    }
    __builtin_amdgcn_s_barrier();          // B: all done reading cur; safe to overwrite
  }

  // epilogue: two row-halves through LDS, then fused LSTM elementwise
#pragma unroll
  for (int half = 0; half < 2; ++half) {
    if ((wr >> 1) == half) {               // waves wr {0,1} -> rows 0..63; {2,3} -> 64..127
#pragma unroll
      for (int ni = 0; ni < 4; ++ni) {
        int col = wc * 64 + ni * 16 + l15;
        float bv = bias[n0 + col];
#pragma unroll
        for (int mi = 0; mi < 2; ++mi)
#pragma unroll
          for (int r = 0; r < 4; ++r)
            ldsF[((wr & 1) * 32 + mi * 16 + l4 * 4 + r) * 132 + col] = acc[mi][ni][r] + bv;
      }
    }
    __syncthreads();
#pragma unroll
    for (int k = 0; k < 4; ++k) {
      int p = tid + k * 512;
      int rl = p >> 5, f = p & 31;
      int n = m0 + half * 64 + rl;
      if (n < N_NODES) {
        float4 pre = *(const float4*)&ldsF[rl * 132 + f * 4];
        int dg = (n0 >> 2) + f;
        float ig = __builtin_amdgcn_rcpf(1.f + __expf(-pre.x));
        float fg = __builtin_amdgcn_rcpf(1.f + __expf(-pre.y));
        float ec = __expf(-2.f * fabsf(pre.z));
        float tg = __builtin_copysignf((1.f - ec) * __builtin_amdgcn_rcpf(1.f + ec), pre.z);
        float og = __builtin_amdgcn_rcpf(1.f + __expf(-pre.w));
        float cOld = cpre[half * 4 + k];
        float cn = fg * cOld + ig * tg;
        float en = __expf(-2.f * fabsf(cn));
        float th = __builtin_copysignf((1.f - en) * __builtin_amdgcn_rcpf(1.f + en), cn);
        __builtin_nontemporal_store(og * th, out + (size_t)n * 128 + dg);
      }
    }
    __syncthreads();
  }
}

extern "C" void kernel_launch(void* const* d_in, const int* in_sizes, int n_in,
                              void* d_out, int out_size, void* d_ws, size_t ws_size,
                              hipStream_t stream) {
  const float* X  = (const float*)d_in[0];
  const int*   ei = (const int*)d_in[1];
  const float* ew = (const float*)d_in[2];
  const float* H  = (const float*)d_in[3];
  const float* C  = (const float*)d_in[4];
  const float* W  = (const float*)d_in[5];
  const float* b  = (const float*)d_in[6];
  const float* cW = (const float*)d_in[7];
  const float* cb = (const float*)d_in[8];
  float* out = (float*)d_out;
  char* ws = (char*)d_ws;

  float*    deg  = (float*)(ws);                 // 0.5 MB
  int*      cnt  = (int*)(ws + 0x80000);         // 0.5 MB
  int2*     bE   = (int2*)(ws + 0x100000);       // 51.2 MB CAP buckets (row, w)
  ushort_t* U    = (ushort_t*)(ws + 0x3500000);  // 100096 x 512 bf16 = 102.5 MB
  ushort_t* Bt   = (ushort_t*)(ws + 0x9700000);  // 512 KB
  float*    bias = (float*)(ws + 0x9780000);     // 2 KB

  hipMemsetAsync(ws, 0, 0x100000, stream);       // zero deg + cnt

  k_misc<<<27128, 256, 0, stream>>>(ei, ew, X, H, deg, cnt, bE, U, W, b, cW, cb, Bt, bias);
  k_scale<<<N_NODES * CAP / 256, 256, 0, stream>>>(cnt, deg, bE);
  k_gather<1><<<8 * 782, 256, 0, stream>>>(cnt, bE, deg, H, U);
  k_gather<2><<<8 * 782, 256, 0, stream>>>(cnt, bE, deg, H, U);
  k_gemm<<<3128, 512, 0, stream>>>(U, Bt, bias, C, out);
}

// Round 18
// 407.398 us; speedup vs baseline: 1.7981x; 1.7981x over previous
//
#include <hip/hip_runtime.h>

#define N_NODES 100000
#define N_EDGES 1600000
#define CAP 64

typedef unsigned short ushort_t;
typedef __attribute__((ext_vector_type(8))) short bf16x8;
typedef __attribute__((ext_vector_type(4))) float f32x4;
typedef __attribute__((ext_vector_type(4))) int int4e;
typedef __attribute__((ext_vector_type(8))) unsigned short ushort8e;

__device__ __forceinline__ unsigned short f2bf(float f) {
  unsigned int u = __float_as_uint(f);
  u = (u + 0x7FFFu + ((u >> 16) & 1u)) >> 16;
  return (unsigned short)u;
}

// ---- fused preprocessing, role-interleaved by (bid & 7): roles 0-1 deg atomics,
// roles 2-3 bucket scatter (raw ew), 4-7 pack X,H -> U bf16 + B^T/bias ----
__global__ __launch_bounds__(256) void k_misc(
    const int* __restrict__ ei, const float* __restrict__ ew,
    const float* __restrict__ X, const float* __restrict__ H,
    float* __restrict__ deg, int* __restrict__ cnt, int2* __restrict__ bE,
    ushort_t* __restrict__ U,
    const float* __restrict__ W, const float* __restrict__ b,
    const float* __restrict__ cW, const float* __restrict__ cb,
    ushort_t* __restrict__ Bt, float* __restrict__ bias) {
  int bid = blockIdx.x;
  int role = bid & 7, q = bid >> 3;          // q < 3391
  if (role < 2) {                            // deg atomics
    int e = (q * 2 + role) * 256 + threadIdx.x;
    if (e < N_EDGES) atomicAdd(&deg[ei[e]], ew[e]);
  } else if (role < 4) {                     // bucket by dst: (row, raw ew)
    int e = (q * 2 + (role - 2)) * 256 + threadIdx.x;
    if (e < N_EDGES) {
      int r = ei[e], c = ei[N_EDGES + e];
      float w = ew[e];
      int pos = atomicAdd(&cnt[c], 1);
      if (pos < CAP) bE[c * CAP + pos] = make_int2(r, __float_as_int(w));
    }
  } else {                                   // streaming: pack then bt
    int s = q * 4 + (role - 4);              // s < 13564
    if (s < 12500) {                         // pack X (cols 0-127), H (128-255)
      int i = s * 256 + threadIdx.x;         // i < 3.2M exactly
      int n = i >> 5, qq = i & 31;
      float4 x = *(const float4*)(X + (size_t)n * 128 + qq * 4);
      float4 h = *(const float4*)(H + (size_t)n * 128 + qq * 4);
      ushort4 a, bb;
      a.x = f2bf(x.x); a.y = f2bf(x.y); a.z = f2bf(x.z); a.w = f2bf(x.w);
      bb.x = f2bf(h.x); bb.y = f2bf(h.y); bb.z = f2bf(h.z); bb.w = f2bf(h.w);
      *(ushort4*)(U + (size_t)n * 512 + qq * 4) = a;
      *(ushort4*)(U + (size_t)n * 512 + 128 + qq * 4) = bb;
    } else if (s < 13524) {                  // B^T [512 j][512 k], j = d*4+g; bias
      int idx = (s - 12500) * 256 + threadIdx.x;
      int j = idx >> 9, k = idx & 511;
      int dd = j >> 2, g = j & 3;
      float v;
      if (k < 128) v = W[(g * 128 + k) * 128 + dd];
      else {
        int kk = k - 128;
        int blk = kk >> 7;
        v = cW[((g * 3 + blk) * 128 + (kk & 127)) * 128 + dd];
      }
      Bt[idx] = f2bf(v);
      if (k == 0) bias[j] = b[g * 128 + dd] + cb[g * 128 + dd];
    }
  }
}

// ---- post-pass: bE[slot].w = rsqrt(deg[row]) * raw_ew (deg now complete) ----
__global__ __launch_bounds__(256) void k_scale(
    const int* __restrict__ cnt, const float* __restrict__ deg,
    int2* __restrict__ bE) {
  int slot = blockIdx.x * 256 + threadIdx.x;     // grid covers N_NODES*CAP exactly
  int node = slot >> 6, i = slot & 63;
  int cn = cnt[node]; if (cn > CAP) cn = CAP;
  if (i < cn) {
    int2 p = bE[slot];
    float d = deg[p.x];
    float w = d > 0.f ? rsqrtf(d) * __int_as_float(p.y) : 0.f;
    bE[slot].y = __float_as_int(w);
  }
}

// FMA of one bf16-packed row (int4e = 8 bf16) into 8-col accumulator A
#define FMA8(A, Wt, R) { \
  A[0] = fmaf(Wt, __uint_as_float((unsigned)R.x << 16), A[0]); \
  A[1] = fmaf(Wt, __uint_as_float((unsigned)R.x & 0xffff0000u), A[1]); \
  A[2] = fmaf(Wt, __uint_as_float((unsigned)R.y << 16), A[2]); \
  A[3] = fmaf(Wt, __uint_as_float((unsigned)R.y & 0xffff0000u), A[3]); \
  A[4] = fmaf(Wt, __uint_as_float((unsigned)R.z << 16), A[4]); \
  A[5] = fmaf(Wt, __uint_as_float((unsigned)R.z & 0xffff0000u), A[5]); \
  A[6] = fmaf(Wt, __uint_as_float((unsigned)R.w << 16), A[6]); \
  A[7] = fmaf(Wt, __uint_as_float((unsigned)R.w & 0xffff0000u), A[7]); }

// ---- bf16-source gather: 16 lanes/node (16B each), 16 nodes/block, 8-deep ILP ----
template <int PHASE>
__global__ __launch_bounds__(256) void k_gather(
    const int* __restrict__ cnt, const int2* __restrict__ bE,
    const float* __restrict__ deg, const float* __restrict__ H,
    ushort_t* __restrict__ U) {
  int g = threadIdx.x >> 4, lane = threadIdx.x & 15;
  int node = blockIdx.x * 16 + g;
  if (node >= N_NODES) return;
  int cn = cnt[node]; if (cn > CAP) cn = CAP;
  const int2* be = bE + node * CAP;
  const ushort_t* sb = U + (PHASE == 1 ? 128 : 256) + lane * 8;
  float dc = deg[node];
  float sc = dc > 0.f ? -rsqrtf(dc) : 0.f;   // -dinv[c], factored out of the sum

  float a0[8] = {}, a1[8] = {}, a2[8] = {}, a3[8] = {};
  float a4[8] = {}, a5[8] = {}, a6[8] = {}, a7[8] = {};
  int i = 0;
  for (; i + 8 <= cn; i += 8) {
    int4e p0 = __builtin_nontemporal_load((const int4e*)(be + i));
    int4e p1 = __builtin_nontemporal_load((const int4e*)(be + i + 2));
    int4e p2 = __builtin_nontemporal_load((const int4e*)(be + i + 4));
    int4e p3 = __builtin_nontemporal_load((const int4e*)(be + i + 6));
    int4e r0 = *(const int4e*)(sb + (size_t)p0.x * 512);
    int4e r1 = *(const int4e*)(sb + (size_t)p0.z * 512);
    int4e r2 = *(const int4e*)(sb + (size_t)p1.x * 512);
    int4e r3 = *(const int4e*)(sb + (size_t)p1.z * 512);
    int4e r4 = *(const int4e*)(sb + (size_t)p2.x * 512);
    int4e r5 = *(const int4e*)(sb + (size_t)p2.z * 512);
    int4e r6 = *(const int4e*)(sb + (size_t)p3.x * 512);
    int4e r7 = *(const int4e*)(sb + (size_t)p3.z * 512);
    FMA8(a0, __int_as_float(p0.y), r0); FMA8(a1, __int_as_float(p0.w), r1);
    FMA8(a2, __int_as_float(p1.y), r2); FMA8(a3, __int_as_float(p1.w), r3);
    FMA8(a4, __int_as_float(p2.y), r4); FMA8(a5, __int_as_float(p2.w), r5);
    FMA8(a6, __int_as_float(p3.y), r6); FMA8(a7, __int_as_float(p3.w), r7);
  }
  for (; i + 4 <= cn; i += 4) {
    int4e p0 = __builtin_nontemporal_load((const int4e*)(be + i));
    int4e p1 = __builtin_nontemporal_load((const int4e*)(be + i + 2));
    int4e r0 = *(const int4e*)(sb + (size_t)p0.x * 512);
    int4e r1 = *(const int4e*)(sb + (size_t)p0.z * 512);
    int4e r2 = *(const int4e*)(sb + (size_t)p1.x * 512);
    int4e r3 = *(const int4e*)(sb + (size_t)p1.z * 512);
    FMA8(a0, __int_as_float(p0.y), r0); FMA8(a1, __int_as_float(p0.w), r1);
    FMA8(a2, __int_as_float(p1.y), r2); FMA8(a3, __int_as_float(p1.w), r3);
  }
  for (; i < cn; ++i) {
    int2 p = be[i];
    int4e r0 = *(const int4e*)(sb + (size_t)p.x * 512);
    FMA8(a0, __int_as_float(p.y), r0);
  }
  float o[8];
#pragma unroll
  for (int j = 0; j < 8; ++j)
    o[j] = sc * (((a0[j] + a1[j]) + (a2[j] + a3[j])) +
                 ((a4[j] + a5[j]) + (a6[j] + a7[j])));

  if (PHASE == 1) {
    ushort8e u;
#pragma unroll
    for (int j = 0; j < 8; ++j) u[j] = f2bf(o[j]);
    __builtin_nontemporal_store(u, (ushort8e*)(U + (size_t)node * 512 + 256 + lane * 8));
  } else {
    float4 hlo = *(const float4*)(H + (size_t)node * 128 + lane * 8);
    float4 hhi = *(const float4*)(H + (size_t)node * 128 + lane * 8 + 4);
    ushort8e u;
    u[0] = f2bf(2.f * o[0] - hlo.x); u[1] = f2bf(2.f * o[1] - hlo.y);
    u[2] = f2bf(2.f * o[2] - hlo.z); u[3] = f2bf(2.f * o[3] - hlo.w);
    u[4] = f2bf(2.f * o[4] - hhi.x); u[5] = f2bf(2.f * o[5] - hhi.y);
    u[6] = f2bf(2.f * o[6] - hhi.z); u[7] = f2bf(2.f * o[7] - hhi.w);
    __builtin_nontemporal_store(u, (ushort8e*)(U + (size_t)node * 512 + 384 + lane * 8));
  }
}

// ---- fused GEMM: same 2-phase counted-vmcnt pipeline, 512 threads (8 waves of
// 32x64) on the 128x128 tile -> 16 waves/CU (2x TLP) at same 64KB LDS ----
__global__ __launch_bounds__(512, 4) void k_gemm(
    const ushort_t* __restrict__ U, const ushort_t* __restrict__ Bt,
    const float* __restrict__ bias, const float* __restrict__ C,
    float* __restrict__ out) {
  __shared__ char ldsRaw[65536];     // 2 x (16K A + 16K B); epilogue reuses as f32 tile
  char* ldsA0 = ldsRaw;
  char* ldsB0 = ldsRaw + 16384;
  char* ldsA1 = ldsRaw + 32768;
  char* ldsB1 = ldsRaw + 49152;
  float* ldsF = (float*)ldsRaw;

  const int tid = threadIdx.x;
  const int lane = tid & 63;
  const int w = tid >> 6;            // 8 waves
  const int wr = w >> 1, wc = w & 1; // 4x2 wave grid: 32-row x 64-col sub-tiles
  // XCD-bijective swizzle: 3128 = 8*391; 4 n-tiles of an m-panel stay in one XCD
  const int b = blockIdx.x;
  const int g = (b & 7) * 391 + (b >> 3);
  const int m0 = (g >> 2) * 128;
  const int n0 = (g & 3) * 128;
  const int l15 = lane & 15;
  const int l4 = lane >> 4;

  // stage half h of tile kt: each thread 1 A + 1 B global_load_lds (16B)
  auto stage_half = [&](int kt, char* la_base, char* lb_base, int h) {
    const int k0 = kt * 64;
    int s = h * 512 + tid;
    int row = s >> 3;
    int cs = (s & 7) ^ (row & 7);          // inverse-swizzled global source chunk
    const ushort_t* ga = U + (size_t)(m0 + row) * 512 + k0 + cs * 8;
    const ushort_t* gb = Bt + (size_t)(n0 + row) * 512 + k0 + cs * 8;
    char* la = la_base + (h * 512 + (tid & 448)) * 16;    // wave-uniform base
    char* lb = lb_base + (h * 512 + (tid & 448)) * 16;
    __builtin_amdgcn_global_load_lds((const __attribute__((address_space(1))) void*)ga,
                                     (__attribute__((address_space(3))) void*)la, 16, 0, 0);
    __builtin_amdgcn_global_load_lds((const __attribute__((address_space(1))) void*)gb,
                                     (__attribute__((address_space(3))) void*)lb, 16, 0, 0);
  };

  // C prefetch (epilogue operand), nontemporal (single-touch, keep out of L2)
  const int fcol = tid & 31;
  const int rbase = tid >> 5;              // 0..15
  float cpre[8];
#pragma unroll
  for (int half = 0; half < 2; ++half)
#pragma unroll
    for (int k = 0; k < 4; ++k) {
      int n = m0 + half * 64 + rbase + k * 16;
      int dg = (n0 >> 2) + fcol;
      cpre[half * 4 + k] = (n < N_NODES)
          ? __builtin_nontemporal_load(C + (size_t)n * 128 + dg) : 0.f;
    }

  // loop-invariant swizzled LDS read offsets (sub-tile rows are multiples of 16)
  int offA[2][2], offB[2][4];
#pragma unroll
  for (int ks = 0; ks < 2; ++ks) {
    int slot = ((ks * 4 + l4) ^ (l15 & 7)) * 16;
#pragma unroll
    for (int i = 0; i < 2; ++i)
      offA[ks][i] = (wr * 32 + i * 16 + l15) * 128 + slot;
#pragma unroll
    for (int i = 0; i < 4; ++i)
      offB[ks][i] = (wc * 64 + i * 16 + l15) * 128 + slot;
  }

  f32x4 acc[2][4] = {};

  stage_half(0, ldsA0, ldsB0, 0);
  stage_half(0, ldsA0, ldsB0, 1);          // 4 loads/thread outstanding

  for (int kt = 0; kt < 8; ++kt) {
    char* curA = (kt & 1) ? ldsA1 : ldsA0;
    char* curB = (kt & 1) ? ldsB1 : ldsB0;
    char* nA = (kt & 1) ? ldsA0 : ldsA1;
    char* nB = (kt & 1) ? ldsB0 : ldsB1;
    if (kt < 7) {
      stage_half(kt + 1, nA, nB, 0);       // 2 loads -> 6 outstanding
      asm volatile("s_waitcnt vmcnt(2)" ::: "memory");  // stage(kt) landed; half0(kt+1) in flight
    } else {
      asm volatile("s_waitcnt vmcnt(0)" ::: "memory");
    }
    __builtin_amdgcn_s_barrier();          // A: cur fully staged for all threads
    __builtin_amdgcn_sched_barrier(0);

    // ---- sub-phase ks=0 ----
    {
      bf16x8 af[2], bfr[4];
#pragma unroll
      for (int mi = 0; mi < 2; ++mi) af[mi] = *(const bf16x8*)(curA + offA[0][mi]);
#pragma unroll
      for (int ni = 0; ni < 4; ++ni) bfr[ni] = *(const bf16x8*)(curB + offB[0][ni]);
      asm volatile("s_waitcnt lgkmcnt(0)" ::: "memory");
      __builtin_amdgcn_sched_barrier(0);
      __builtin_amdgcn_s_setprio(1);
#pragma unroll
      for (int mi = 0; mi < 2; ++mi)
#pragma unroll
        for (int ni = 0; ni < 4; ++ni)
          acc[mi][ni] = __builtin_amdgcn_mfma_f32_16x16x32_bf16(af[mi], bfr[ni], acc[mi][ni], 0, 0, 0);
      __builtin_amdgcn_s_setprio(0);
    }
    if (kt < 7) stage_half(kt + 1, nA, nB, 1);  // 2 loads
    // ---- sub-phase ks=1 ----
    {
      bf16x8 af[2], bfr[4];
#pragma unroll
      for (int mi = 0; mi < 2; ++mi) af[mi] = *(const bf16x8*)(curA + offA[1][mi]);
#pragma unroll
      for (int ni = 0; ni < 4; ++ni) bfr[ni] = *(const bf16x8*)(curB + offB[1][ni]);
      asm volatile("s_waitcnt lgkmcnt(0)" ::: "memory");
      __builtin_amdgcn_sched_barrier(0);
      __builtin_amdgcn_s_setprio(1);
#pragma unroll
      for (int mi = 0; mi < 2; ++mi)
#pragma unroll
        for (int ni = 0; ni < 4; ++ni)
          acc[mi][ni] = __builtin_amdgcn_mfma_f32_16x16x32_bf16(af[mi], bfr[ni], acc[mi][ni], 0, 0, 0);
      __builtin_amdgcn_s_setprio(0);
    }
    __builtin_amdgcn_s_barrier();          // B: all done reading cur; safe to overwrite
  }

  // epilogue: two row-halves through LDS, then fused LSTM elementwise
#pragma unroll
  for (int half = 0; half < 2; ++half) {
    if ((wr >> 1) == half) {               // waves wr {0,1} -> rows 0..63; {2,3} -> 64..127
#pragma unroll
      for (int ni = 0; ni < 4; ++ni) {
        int col = wc * 64 + ni * 16 + l15;
        float bv = bias[n0 + col];
#pragma unroll
        for (int mi = 0; mi < 2; ++mi)
#pragma unroll
          for (int r = 0; r < 4; ++r)
            ldsF[((wr & 1) * 32 + mi * 16 + l4 * 4 + r) * 132 + col] = acc[mi][ni][r] + bv;
      }
    }
    __syncthreads();
#pragma unroll
    for (int k = 0; k < 4; ++k) {
      int p = tid + k * 512;
      int rl = p >> 5, f = p & 31;
      int n = m0 + half * 64 + rl;
      if (n < N_NODES) {
        float4 pre = *(const float4*)&ldsF[rl * 132 + f * 4];
        int dg = (n0 >> 2) + f;
        float ig = __builtin_amdgcn_rcpf(1.f + __expf(-pre.x));
        float fg = __builtin_amdgcn_rcpf(1.f + __expf(-pre.y));
        float ec = __expf(-2.f * fabsf(pre.z));
        float tg = __builtin_copysignf((1.f - ec) * __builtin_amdgcn_rcpf(1.f + ec), pre.z);
        float og = __builtin_amdgcn_rcpf(1.f + __expf(-pre.w));
        float cOld = cpre[half * 4 + k];
        float cn = fg * cOld + ig * tg;
        float en = __expf(-2.f * fabsf(cn));
        float th = __builtin_copysignf((1.f - en) * __builtin_amdgcn_rcpf(1.f + en), cn);
        __builtin_nontemporal_store(og * th, out + (size_t)n * 128 + dg);
      }
    }
    __syncthreads();
  }
}

extern "C" void kernel_launch(void* const* d_in, const int* in_sizes, int n_in,
                              void* d_out, int out_size, void* d_ws, size_t ws_size,
                              hipStream_t stream) {
  const float* X  = (const float*)d_in[0];
  const int*   ei = (const int*)d_in[1];
  const float* ew = (const float*)d_in[2];
  const float* H  = (const float*)d_in[3];
  const float* C  = (const float*)d_in[4];
  const float* W  = (const float*)d_in[5];
  const float* b  = (const float*)d_in[6];
  const float* cW = (const float*)d_in[7];
  const float* cb = (const float*)d_in[8];
  float* out = (float*)d_out;
  char* ws = (char*)d_ws;

  float*    deg  = (float*)(ws);                 // 0.5 MB
  int*      cnt  = (int*)(ws + 0x80000);         // 0.5 MB
  int2*     bE   = (int2*)(ws + 0x100000);       // 51.2 MB CAP buckets (row, w)
  ushort_t* U    = (ushort_t*)(ws + 0x3500000);  // 100096 x 512 bf16 = 102.5 MB
  ushort_t* Bt   = (ushort_t*)(ws + 0x9700000);  // 512 KB
  float*    bias = (float*)(ws + 0x9780000);     // 2 KB

  hipMemsetAsync(ws, 0, 0x100000, stream);       // zero deg + cnt

  k_misc<<<27128, 256, 0, stream>>>(ei, ew, X, H, deg, cnt, bE, U, W, b, cW, cb, Bt, bias);
  k_scale<<<N_NODES * CAP / 256, 256, 0, stream>>>(cnt, deg, bE);
  k_gather<1><<<(N_NODES + 15) / 16, 256, 0, stream>>>(cnt, bE, deg, H, U);
  k_gather<2><<<(N_NODES + 15) / 16, 256, 0, stream>>>(cnt, bE, deg, H, U);
  k_gemm<<<3128, 512, 0, stream>>>(U, Bt, bias, C, out);
}